// Round 7
// baseline (547.881 us; speedup 1.0000x reference)
//
#include <hip/hip_runtime.h>
#include <hip/hip_cooperative_groups.h>

namespace cg = cooperative_groups;

#define N_NODES 50000
#define D_FEAT 64
#define N_NNZ 800000
#define N_ENT 65536   // 2 * 32768 edge endpoints

typedef unsigned int uint32;
typedef unsigned short ushort16;

// Plane strides for plane-major [3][N][64] bf16 tables
#define PLANE_U4 ((size_t)N_NODES * 8)    // in uint4 (16B) units
#define PLANE_US ((size_t)N_NODES * 64)   // in ushort units

// ---- bf16 helpers ---------------------------------------------------------
__device__ __forceinline__ uint32 rne1(float a) {
    uint32 u = __float_as_uint(a);
    return (u + 0x7FFFu + ((u >> 16) & 1u)) >> 16;
}
__device__ __forceinline__ uint32 rne2(float a, float b) {   // pack [a:lo, b:hi]
    return rne1(a) | (rne1(b) << 16);
}
__device__ __forceinline__ float bf_lo(uint32 u) { return __uint_as_float(u << 16); }
__device__ __forceinline__ float bf_hi(uint32 u) { return __uint_as_float(u & 0xFFFF0000u); }
__device__ __forceinline__ void unpack8(const uint4 v, float* f) {
    f[0] = bf_lo(v.x); f[1] = bf_hi(v.x);
    f[2] = bf_lo(v.y); f[3] = bf_hi(v.y);
    f[4] = bf_lo(v.z); f[5] = bf_hi(v.z);
    f[6] = bf_lo(v.w); f[7] = bf_hi(v.w);
}
__device__ __forceinline__ float bf1(ushort16 u) { return __uint_as_float(((uint32)u) << 16); }

// ---------------------------------------------------------------------------
// ONE cooperative kernel = whole pipeline. Phases separated by grid.sync():
//   0: rowptr+scal (binary search) ; pack x -> bf16
//   1: y1 = degrev * spmm(x3)            (octet-per-row, plane-major out)
//   2: y2 = degrev * spmm(y1) - x3       (plane-split passes, 4-way MLP)
//   3: output gather + [64,9] transpose via LDS
// Rationale: 8 serialized dispatches -> 1; kills inter-dispatch gaps +
// ramp/drain, and surfaces OUR work as the top rocprof dispatch (everything
// was hidden below the harness's 88us fills until now).
// Cooperative rules: no early return; every thread reaches every grid.sync.
// ---------------------------------------------------------------------------
__global__ __launch_bounds__(256, 4) void fused_all(
    const float* __restrict__ x, const float* __restrict__ deg,
    const int* __restrict__ adj_row, const int* __restrict__ adj_col,
    const int* __restrict__ edge,
    int* __restrict__ row_ptr, float4* __restrict__ scal,
    uint32* __restrict__ xh, uint4* __restrict__ y1h, uint4* __restrict__ y2h,
    float* __restrict__ out)
{
    __shared__ __align__(16) float lds[4][576];
    cg::grid_group grid = cg::this_grid();

    const int tid      = threadIdx.x;
    const int nthreads = gridDim.x * 256;
    const int gthread  = blockIdx.x * 256 + tid;

    // ---- phase 0a: CSR row pointers + per-node scalars --------------------
    for (int r = gthread; r <= N_NODES; r += nthreads) {
        int lo = 0, hi = N_NNZ;          // first idx with adj_row[idx] >= r
        while (lo < hi) {
            int mid = (lo + hi) >> 1;
            if (adj_row[mid] < r) lo = mid + 1; else hi = mid;
        }
        row_ptr[r] = lo;
        if (r < N_NODES) {
            float d  = deg[r];
            float sq = sqrtf(d);
            scal[r] = make_float4(1.0f / d, 1.0f / sq, sq, 0.0f);
        }
    }
    // ---- phase 0b: x (fp32) -> xh (bf16 pairs) ----------------------------
    {
        const float2* x2 = (const float2*)x;
        for (int i = gthread; i < N_NODES * 32; i += nthreads) {
            float2 v = x2[i];
            xh[i] = rne2(v.x, v.y);
        }
    }
    grid.sync();

    // ---- phase 1: y1 = degrev * spmm(x3) ----------------------------------
    {
        const uint4* xh4 = (const uint4*)xh;
        const int f        = tid & 7;                 // feature block
        const int waveslot = blockIdx.x * 4 + (tid >> 6);
        const int octet    = (tid & 63) >> 3;
        const int rows_per = gridDim.x * 4 * 8;
        for (int base = 0; base < N_NODES; base += rows_per) {
            int r = base + waveslot * 8 + octet;
            if (r < N_NODES) {
                int s = row_ptr[r], e = row_ptr[r + 1];
                int cnt = e - s;
                float a0[8], a1[8], a2[8];
#pragma unroll
                for (int j = 0; j < 8; ++j) { a0[j] = 0.f; a1[j] = 0.f; a2[j] = 0.f; }
                int i = 0;
                for (; i + 2 <= cnt; i += 2) {
                    int c0 = adj_col[s + i];
                    int c1 = adj_col[s + i + 1];
                    uint4 xv0 = xh4[(size_t)c0 * 8 + f];
                    uint4 xv1 = xh4[(size_t)c1 * 8 + f];
                    float4 sc0 = scal[c0];
                    float4 sc1 = scal[c1];
                    float xf0[8], xf1[8];
                    unpack8(xv0, xf0); unpack8(xv1, xf1);
#pragma unroll
                    for (int j = 0; j < 8; ++j) {
                        a0[j] += xf0[j];
                        a1[j] += xf0[j] * sc0.y;
                        a2[j] += xf0[j] * sc0.z;
                        a0[j] += xf1[j];
                        a1[j] += xf1[j] * sc1.y;
                        a2[j] += xf1[j] * sc1.z;
                    }
                }
                if (i < cnt) {
                    int c = adj_col[s + i];
                    uint4 xv = xh4[(size_t)c * 8 + f];
                    float4 sc = scal[c];
                    float xf[8]; unpack8(xv, xf);
#pragma unroll
                    for (int j = 0; j < 8; ++j) {
                        a0[j] += xf[j];
                        a1[j] += xf[j] * sc.y;
                        a2[j] += xf[j] * sc.z;
                    }
                }
                float dr = scal[r].x;
                size_t bo = (size_t)r * 8 + f;
                y1h[bo]              = make_uint4(rne2(a0[0]*dr, a0[1]*dr), rne2(a0[2]*dr, a0[3]*dr),
                                                  rne2(a0[4]*dr, a0[5]*dr), rne2(a0[6]*dr, a0[7]*dr));
                y1h[bo + PLANE_U4]   = make_uint4(rne2(a1[0]*dr, a1[1]*dr), rne2(a1[2]*dr, a1[3]*dr),
                                                  rne2(a1[4]*dr, a1[5]*dr), rne2(a1[6]*dr, a1[7]*dr));
                y1h[bo + 2*PLANE_U4] = make_uint4(rne2(a2[0]*dr, a2[1]*dr), rne2(a2[2]*dr, a2[3]*dr),
                                                  rne2(a2[4]*dr, a2[5]*dr), rne2(a2[6]*dr, a2[7]*dr));
            }
        }
    }
    grid.sync();

    // ---- phase 2: y2 = degrev * spmm(y1) - x3, plane-split ---------------
    {
        const float4* x4 = (const float4*)x;
        const int f        = tid & 7;
        const int waveslot = blockIdx.x * 4 + (tid >> 6);
        const int octet    = (tid & 63) >> 3;
        const int rows_per = gridDim.x * 4 * 8;
        for (int g = 0; g < 3; ++g) {
            const uint4* yp = y1h + (size_t)g * PLANE_U4;
            for (int base = 0; base < N_NODES; base += rows_per) {
                int r = base + waveslot * 8 + octet;
                if (r < N_NODES) {
                    int s = row_ptr[r], e = row_ptr[r + 1];
                    int cnt = e - s;
                    float a[8];
#pragma unroll
                    for (int j = 0; j < 8; ++j) a[j] = 0.f;
                    int i = 0;
                    for (; i + 4 <= cnt; i += 4) {        // 4 gathers in flight
                        int c0 = adj_col[s + i];
                        int c1 = adj_col[s + i + 1];
                        int c2 = adj_col[s + i + 2];
                        int c3 = adj_col[s + i + 3];
                        uint4 b0 = yp[(size_t)c0 * 8 + f];
                        uint4 b1 = yp[(size_t)c1 * 8 + f];
                        uint4 b2 = yp[(size_t)c2 * 8 + f];
                        uint4 b3 = yp[(size_t)c3 * 8 + f];
                        float f0[8], f1[8], f2[8], f3[8];
                        unpack8(b0, f0); unpack8(b1, f1); unpack8(b2, f2); unpack8(b3, f3);
#pragma unroll
                        for (int j = 0; j < 8; ++j)
                            a[j] += (f0[j] + f1[j]) + (f2[j] + f3[j]);
                    }
                    for (; i < cnt; ++i) {
                        int c = adj_col[s + i];
                        uint4 b = yp[(size_t)c * 8 + f];
                        float fv[8]; unpack8(b, fv);
#pragma unroll
                        for (int j = 0; j < 8; ++j) a[j] += fv[j];
                    }
                    float4 sc = scal[r];             // {1/d, rsqrt, sqrt, 0}
                    float w = (g == 0) ? 1.0f : ((g == 1) ? sc.y : sc.z);
                    float4 xa = x4[(size_t)r * 16 + f * 2];
                    float4 xb = x4[(size_t)r * 16 + f * 2 + 1];
                    float xr[8] = {xa.x, xa.y, xa.z, xa.w, xb.x, xb.y, xb.z, xb.w};
                    float v[8];
#pragma unroll
                    for (int j = 0; j < 8; ++j) v[j] = sc.x * a[j] - xr[j] * w;
                    uint4* yr = y2h + (size_t)g * PLANE_U4 + (size_t)r * 8 + f;
                    yr[0] = make_uint4(rne2(v[0], v[1]), rne2(v[2], v[3]),
                                       rne2(v[4], v[5]), rne2(v[6], v[7]));
                }
            }
        }
    }
    grid.sync();

    // ---- phase 3: output gather + [64,9] transpose through LDS -----------
    {
        const ushort16* y1s = (const ushort16*)y1h;
        const ushort16* y2s = (const ushort16*)y2h;
        const int wave = tid >> 6;
        const int t    = tid & 63;
        for (int ent0 = blockIdx.x * 4; ent0 < N_ENT; ent0 += gridDim.x * 4) {
            int ent = ent0 + wave;                     // N_ENT%4==0: always valid
            int n = edge[ent];
            float4 sc = scal[n];                       // {1/d, rsqrt, sqrt, 0}
            float xv = x[n * D_FEAT + t];
            size_t nb = (size_t)n * 64 + t;

            float h[9];
            h[0] = xv;               h[1] = xv * sc.y;               h[2] = xv * sc.z;
            h[3] = bf1(y1s[nb]);     h[4] = bf1(y1s[nb + PLANE_US]); h[5] = bf1(y1s[nb + 2*PLANE_US]);
            h[6] = bf1(y2s[nb]);     h[7] = bf1(y2s[nb + PLANE_US]); h[8] = bf1(y2s[nb + 2*PLANE_US]);

#pragma unroll
            for (int g = 0; g < 9; ++g) lds[wave][t * 9 + g] = h[g];
            __syncthreads();

            const float4* l4 = (const float4*)lds[wave];
            float4* o4 = (float4*)(out + (size_t)ent * 576);
            o4[t]      = l4[t];
            o4[t + 64] = l4[t + 64];
            if (t < 16) o4[t + 128] = l4[t + 128];
            __syncthreads();                           // protect lds reuse next iter
        }
    }
}

// ---------------------------------------------------------------------------
extern "C" void kernel_launch(void* const* d_in, const int* in_sizes, int n_in,
                              void* d_out, int out_size, void* d_ws, size_t ws_size,
                              hipStream_t stream) {
    const float* x       = (const float*)d_in[0];   // [N, 64]
    const float* deg     = (const float*)d_in[1];   // [N, 1]
    const int*   adj_row = (const int*)d_in[2];     // [nnz] sorted
    const int*   adj_col = (const int*)d_in[3];     // [nnz]
    const int*   edge    = (const int*)d_in[4];     // [2, 32768]
    float* out = (float*)d_out;

    // Workspace (rewritten fully every call)
    char* ws = (char*)d_ws;
    size_t off = 0;
    int*    row_ptr = (int*)ws;            off = ((size_t)(N_NODES + 1) * 4 + 255) & ~(size_t)255;
    float4* scal    = (float4*)(ws + off); off += (size_t)N_NODES * 16;
    uint32* xh      = (uint32*)(ws + off); off += (size_t)N_NODES * 64 * 2;
    off = (off + 255) & ~(size_t)255;
    uint4*  y1h     = (uint4*)(ws + off);  off += (size_t)N_NODES * 192 * 2;
    off = (off + 255) & ~(size_t)255;
    uint4*  y2h     = (uint4*)(ws + off);

    // Cooperative grid: blocks/CU from occupancy query (cached), 256 CUs.
    static int coop_grid = -1;
    if (coop_grid < 0) {
        int occ = 0;
        hipOccupancyMaxActiveBlocksPerMultiprocessor(&occ, fused_all, 256, 0);
        if (occ < 1) occ = 1;
        if (occ > 4) occ = 4;      // __launch_bounds__(256,4) targets 4
        coop_grid = occ * 256;
    }

    void* kargs[] = {
        (void*)&x, (void*)&deg, (void*)&adj_row, (void*)&adj_col, (void*)&edge,
        (void*)&row_ptr, (void*)&scal, (void*)&xh, (void*)&y1h, (void*)&y2h,
        (void*)&out
    };
    hipLaunchCooperativeKernel((void*)fused_all, dim3(coop_grid), dim3(256),
                               kargs, 0, stream);
}

// Round 8
// 256.313 us; speedup vs baseline: 2.1375x; 2.1375x over previous
//
#include <hip/hip_runtime.h>

#define N_NODES 50000
#define D_FEAT 64
#define N_NNZ 800000
#define N_ENT 65536   // 2 * 32768 edge endpoints

typedef unsigned int uint32;
typedef unsigned short ushort16;

// Plane strides for plane-major [3][N][64] bf16 tables
#define PLANE_U4 ((size_t)N_NODES * 8)    // in uint4 (16B) units
#define PLANE_US ((size_t)N_NODES * 64)   // in ushort units

// ---- bf16 helpers ---------------------------------------------------------
__device__ __forceinline__ uint32 rne1(float a) {
    uint32 u = __float_as_uint(a);
    return (u + 0x7FFFu + ((u >> 16) & 1u)) >> 16;
}
__device__ __forceinline__ uint32 rne2(float a, float b) {   // pack [a:lo, b:hi]
    return rne1(a) | (rne1(b) << 16);
}
__device__ __forceinline__ float bf_lo(uint32 u) { return __uint_as_float(u << 16); }
__device__ __forceinline__ float bf_hi(uint32 u) { return __uint_as_float(u & 0xFFFF0000u); }
__device__ __forceinline__ void unpack8(const uint4 v, float* f) {
    f[0] = bf_lo(v.x); f[1] = bf_hi(v.x);
    f[2] = bf_lo(v.y); f[3] = bf_hi(v.y);
    f[4] = bf_lo(v.z); f[5] = bf_hi(v.z);
    f[6] = bf_lo(v.w); f[7] = bf_hi(v.w);
}
__device__ __forceinline__ float bf1(ushort16 u) { return __uint_as_float(((uint32)u) << 16); }

// ---------------------------------------------------------------------------
// 1a) CSR row pointers (binary search over sorted adj_row) + per-node scalars
//     scal[n] = {1/deg, rsqrt(deg), sqrt(deg), 0}
// ---------------------------------------------------------------------------
__global__ void build_rowptr_scal(const int* __restrict__ adj_row,
                                  const float* __restrict__ deg,
                                  int* __restrict__ row_ptr,
                                  float4* __restrict__ scal,
                                  int nnz, int n) {
    int r = blockIdx.x * blockDim.x + threadIdx.x;
    if (r > n) return;
    int lo = 0, hi = nnz;           // first idx with adj_row[idx] >= r
    while (lo < hi) {
        int mid = (lo + hi) >> 1;
        if (adj_row[mid] < r) lo = mid + 1; else hi = mid;
    }
    row_ptr[r] = lo;
    if (r < n) {
        float d  = deg[r];
        float sq = sqrtf(d);
        scal[r] = make_float4(1.0f / d, 1.0f / sq, sq, 0.0f);
    }
}

// 1b) x (fp32) -> xh (bf16 pairs). 50000*64/2 = 1.6M uint32.
__global__ __launch_bounds__(256) void pack_x(const float2* __restrict__ x2,
                                              uint32* __restrict__ xh, int npair) {
    int i = blockIdx.x * blockDim.x + threadIdx.x;
    if (i >= npair) return;
    float2 v = x2[i];
    xh[i] = rne2(v.x, v.y);
}

// ---------------------------------------------------------------------------
// 2) y1 = degrev * spmm(x3). Octet-per-row; 4-way MLP unroll (was 2):
//    8 independent 16B gathers in flight per lane (4 xh + 4 scal).
//    R7 counters showed VALUBusy 5.7% / HBM 10.6% -> pure latency stall;
//    in-flight load count is the lever.
// ---------------------------------------------------------------------------
__global__ __launch_bounds__(256) void spmm1_kernel(
    const uint4* __restrict__ xh, const float4* __restrict__ scal,
    const int* __restrict__ adj_col, const int* __restrict__ row_ptr,
    uint4* __restrict__ y1h, int n) {
    int t    = threadIdx.x & 63;
    int f    = t & 7;                                  // feature block
    int r    = (blockIdx.x * 4 + (threadIdx.x >> 6)) * 8 + (t >> 3);
    if (r >= n) return;

    int s = row_ptr[r], e = row_ptr[r + 1];
    int cnt = e - s;
    float a0[8], a1[8], a2[8];
#pragma unroll
    for (int j = 0; j < 8; ++j) { a0[j] = 0.f; a1[j] = 0.f; a2[j] = 0.f; }

    int i = 0;
    for (; i + 4 <= cnt; i += 4) {
        int c0 = adj_col[s + i];
        int c1 = adj_col[s + i + 1];
        int c2 = adj_col[s + i + 2];
        int c3 = adj_col[s + i + 3];
        uint4 xv0 = xh[(size_t)c0 * 8 + f];
        uint4 xv1 = xh[(size_t)c1 * 8 + f];
        uint4 xv2 = xh[(size_t)c2 * 8 + f];
        uint4 xv3 = xh[(size_t)c3 * 8 + f];
        float4 sc0 = scal[c0];
        float4 sc1 = scal[c1];
        float4 sc2 = scal[c2];
        float4 sc3 = scal[c3];
        float xf0[8], xf1[8], xf2[8], xf3[8];
        unpack8(xv0, xf0); unpack8(xv1, xf1);
        unpack8(xv2, xf2); unpack8(xv3, xf3);
#pragma unroll
        for (int j = 0; j < 8; ++j) {
            a0[j] += (xf0[j] + xf1[j]) + (xf2[j] + xf3[j]);
            a1[j] += (xf0[j] * sc0.y + xf1[j] * sc1.y)
                   + (xf2[j] * sc2.y + xf3[j] * sc3.y);
            a2[j] += (xf0[j] * sc0.z + xf1[j] * sc1.z)
                   + (xf2[j] * sc2.z + xf3[j] * sc3.z);
        }
    }
    for (; i < cnt; ++i) {                         // <=3 scalar tail iters
        int c = adj_col[s + i];
        uint4 xv = xh[(size_t)c * 8 + f];
        float4 sc = scal[c];
        float xf[8]; unpack8(xv, xf);
#pragma unroll
        for (int j = 0; j < 8; ++j) {
            a0[j] += xf[j];
            a1[j] += xf[j] * sc.y;
            a2[j] += xf[j] * sc.z;
        }
    }

    float dr = scal[r].x;
    size_t base = (size_t)r * 8 + f;
    y1h[base]               = make_uint4(rne2(a0[0]*dr, a0[1]*dr), rne2(a0[2]*dr, a0[3]*dr),
                                         rne2(a0[4]*dr, a0[5]*dr), rne2(a0[6]*dr, a0[7]*dr));
    y1h[base + PLANE_U4]    = make_uint4(rne2(a1[0]*dr, a1[1]*dr), rne2(a1[2]*dr, a1[3]*dr),
                                         rne2(a1[4]*dr, a1[5]*dr), rne2(a1[6]*dr, a1[7]*dr));
    y1h[base + 2*PLANE_U4]  = make_uint4(rne2(a2[0]*dr, a2[1]*dr), rne2(a2[2]*dr, a2[3]*dr),
                                         rne2(a2[4]*dr, a2[5]*dr), rne2(a2[6]*dr, a2[7]*dr));
}

// ---------------------------------------------------------------------------
// 3) y2 = degrev * spmm(y1) - x3, one group per pass (blockIdx.y).
//    8-way MLP unroll (was 4): 8 independent 16B gathers in flight per lane.
//    Tail pyramid 4/1 keeps the remainder's serial chain short.
// ---------------------------------------------------------------------------
__global__ __launch_bounds__(256) void spmm2_kernel(
    const float4* __restrict__ x4, const float4* __restrict__ scal,
    const int* __restrict__ adj_col, const int* __restrict__ row_ptr,
    const uint4* __restrict__ y1h, uint4* __restrict__ y2h, int n) {
    int t = threadIdx.x & 63;
    int f = t & 7;
    int r = (blockIdx.x * 4 + (threadIdx.x >> 6)) * 8 + (t >> 3);
    int g = blockIdx.y;
    if (r >= n) return;
    const uint4* yp = y1h + (size_t)g * PLANE_U4;

    int s = row_ptr[r], e = row_ptr[r + 1];
    int cnt = e - s;
    float a[8];
#pragma unroll
    for (int j = 0; j < 8; ++j) a[j] = 0.f;

    int i = 0;
    for (; i + 8 <= cnt; i += 8) {                 // 8 gathers in flight/lane
        int c0 = adj_col[s + i];
        int c1 = adj_col[s + i + 1];
        int c2 = adj_col[s + i + 2];
        int c3 = adj_col[s + i + 3];
        int c4 = adj_col[s + i + 4];
        int c5 = adj_col[s + i + 5];
        int c6 = adj_col[s + i + 6];
        int c7 = adj_col[s + i + 7];
        uint4 b0 = yp[(size_t)c0 * 8 + f];
        uint4 b1 = yp[(size_t)c1 * 8 + f];
        uint4 b2 = yp[(size_t)c2 * 8 + f];
        uint4 b3 = yp[(size_t)c3 * 8 + f];
        uint4 b4 = yp[(size_t)c4 * 8 + f];
        uint4 b5 = yp[(size_t)c5 * 8 + f];
        uint4 b6 = yp[(size_t)c6 * 8 + f];
        uint4 b7 = yp[(size_t)c7 * 8 + f];
        float f0[8], f1[8], f2[8], f3[8], f4[8], f5[8], f6[8], f7[8];
        unpack8(b0, f0); unpack8(b1, f1); unpack8(b2, f2); unpack8(b3, f3);
        unpack8(b4, f4); unpack8(b5, f5); unpack8(b6, f6); unpack8(b7, f7);
#pragma unroll
        for (int j = 0; j < 8; ++j)
            a[j] += ((f0[j] + f1[j]) + (f2[j] + f3[j]))
                  + ((f4[j] + f5[j]) + (f6[j] + f7[j]));
    }
    for (; i + 4 <= cnt; i += 4) {
        int c0 = adj_col[s + i];
        int c1 = adj_col[s + i + 1];
        int c2 = adj_col[s + i + 2];
        int c3 = adj_col[s + i + 3];
        uint4 b0 = yp[(size_t)c0 * 8 + f];
        uint4 b1 = yp[(size_t)c1 * 8 + f];
        uint4 b2 = yp[(size_t)c2 * 8 + f];
        uint4 b3 = yp[(size_t)c3 * 8 + f];
        float f0[8], f1[8], f2[8], f3[8];
        unpack8(b0, f0); unpack8(b1, f1); unpack8(b2, f2); unpack8(b3, f3);
#pragma unroll
        for (int j = 0; j < 8; ++j)
            a[j] += (f0[j] + f1[j]) + (f2[j] + f3[j]);
    }
    for (; i < cnt; ++i) {                         // <=3 scalar tail iters
        int c = adj_col[s + i];
        uint4 b = yp[(size_t)c * 8 + f];
        float fv[8]; unpack8(b, fv);
#pragma unroll
        for (int j = 0; j < 8; ++j) a[j] += fv[j];
    }

    float4 sc = scal[r];                       // {1/d, rsqrt, sqrt, 0}
    float w = (g == 0) ? 1.0f : ((g == 1) ? sc.y : sc.z);
    float4 xa = x4[(size_t)r * 16 + f * 2];
    float4 xb = x4[(size_t)r * 16 + f * 2 + 1];
    float xr[8] = {xa.x, xa.y, xa.z, xa.w, xb.x, xb.y, xb.z, xb.w};
    float v[8];
#pragma unroll
    for (int j = 0; j < 8; ++j) v[j] = sc.x * a[j] - xr[j] * w;

    uint4* yr = y2h + (size_t)g * PLANE_U4 + (size_t)r * 8 + f;
    yr[0] = make_uint4(rne2(v[0], v[1]), rne2(v[2], v[3]),
                       rne2(v[4], v[5]), rne2(v[6], v[7]));
}

// ---------------------------------------------------------------------------
// 4) Output gather + [64,9] transpose through LDS; float4 store path.
//    out[ent, d, g]: g 0..2 = x*{1,rsqrt,sqrt}, g 3..5 = y1, g 6..8 = y2.
//    y1/y2 plane-major: plane stride N*64 ushorts.
// ---------------------------------------------------------------------------
__global__ __launch_bounds__(256) void gather_kernel(
    const float* __restrict__ x, const float4* __restrict__ scal,
    const int* __restrict__ edge, const ushort16* __restrict__ y1h,
    const ushort16* __restrict__ y2h, float* __restrict__ out) {
    __shared__ __align__(16) float lds[4][576];
    int wave = threadIdx.x >> 6;
    int t    = threadIdx.x & 63;
    int ent  = blockIdx.x * 4 + wave;

    int n = edge[ent];
    float4 sc = scal[n];                       // {1/d, rsqrt, sqrt, 0}
    float xv = x[n * D_FEAT + t];
    size_t nb = (size_t)n * 64 + t;

    float h[9];
    h[0] = xv;                      h[1] = xv * sc.y;                h[2] = xv * sc.z;
    h[3] = bf1(y1h[nb]);            h[4] = bf1(y1h[nb + PLANE_US]);  h[5] = bf1(y1h[nb + 2*PLANE_US]);
    h[6] = bf1(y2h[nb]);            h[7] = bf1(y2h[nb + PLANE_US]);  h[8] = bf1(y2h[nb + 2*PLANE_US]);

#pragma unroll
    for (int g = 0; g < 9; ++g) lds[wave][t * 9 + g] = h[g];  // 2-way alias: free
    __syncthreads();

    const float4* l4 = (const float4*)lds[wave];
    float4* o4 = (float4*)(out + (size_t)ent * 576);   // 144 float4 per entry
    o4[t]      = l4[t];
    o4[t + 64] = l4[t + 64];
    if (t < 16) o4[t + 128] = l4[t + 128];
}

// ---------------------------------------------------------------------------
extern "C" void kernel_launch(void* const* d_in, const int* in_sizes, int n_in,
                              void* d_out, int out_size, void* d_ws, size_t ws_size,
                              hipStream_t stream) {
    const float* x       = (const float*)d_in[0];   // [N, 64]
    const float* deg     = (const float*)d_in[1];   // [N, 1]
    const int*   adj_row = (const int*)d_in[2];     // [nnz] sorted
    const int*   adj_col = (const int*)d_in[3];     // [nnz]
    const int*   edge    = (const int*)d_in[4];     // [2, 32768]
    float* out = (float*)d_out;

    // Workspace (rewritten fully every call):
    //   row_ptr : (N+1) int        scal : N float4
    //   xh      : N*64 bf16        y1h  : [3][N][64] bf16   y2h : [3][N][64] bf16
    char* ws = (char*)d_ws;
    size_t off = 0;
    int*    row_ptr = (int*)ws;            off = ((size_t)(N_NODES + 1) * 4 + 255) & ~(size_t)255;
    float4* scal    = (float4*)(ws + off); off += (size_t)N_NODES * 16;
    uint32* xh      = (uint32*)(ws + off); off += (size_t)N_NODES * 64 * 2;
    off = (off + 255) & ~(size_t)255;
    uint4*  y1h     = (uint4*)(ws + off);  off += (size_t)N_NODES * 192 * 2;
    off = (off + 255) & ~(size_t)255;
    uint4*  y2h     = (uint4*)(ws + off);

    int nblk = (N_NODES + 31) / 32;

    build_rowptr_scal<<<(N_NODES + 1 + 255) / 256, 256, 0, stream>>>(
        adj_row, deg, row_ptr, scal, N_NNZ, N_NODES);
    pack_x<<<(N_NODES * 32 + 255) / 256, 256, 0, stream>>>(
        (const float2*)x, xh, N_NODES * 32);
    spmm1_kernel<<<nblk, 256, 0, stream>>>(
        (const uint4*)xh, scal, adj_col, row_ptr, y1h, N_NODES);
    spmm2_kernel<<<dim3(nblk, 3), 256, 0, stream>>>(
        (const float4*)x, scal, adj_col, row_ptr, y1h, y2h, N_NODES);
    gather_kernel<<<N_ENT / 4, 256, 0, stream>>>(
        x, scal, edge, (const ushort16*)y1h, (const ushort16*)y2h, out);
}